// Round 6
// baseline (182.463 us; speedup 1.0000x reference)
//
#include <hip/hip_runtime.h>
#include <math.h>

// Problem constants (fixed by reference setup_inputs)
constexpr int B = 32, C = 512, N = 1024;   // N = H*W

typedef float f32x4 __attribute__((ext_vector_type(4)));
typedef _Float16 f16x8 __attribute__((ext_vector_type(8)));
typedef unsigned short u16x4 __attribute__((ext_vector_type(4)));
typedef unsigned short u16x8 __attribute__((ext_vector_type(8)));

// fp16 bit helpers
__device__ __forceinline__ unsigned short f32_to_f16u(float v) {
  union { _Float16 h; unsigned short u; } cv; cv.h = (_Float16)v; return cv.u;
}
__device__ __forceinline__ float f16u_to_f32(unsigned short u) {
  union { _Float16 h; unsigned short u; } cv; cv.u = u; return (float)cv.h;
}

// async global->LDS, 16B per lane; LDS dest = wave-uniform base + lane*16
__device__ __forceinline__ void glds16(const void* g, void* l) {
  __builtin_amdgcn_global_load_lds((const __attribute__((address_space(1))) void*)g,
                                   (__attribute__((address_space(3))) void*)l, 16, 0, 0);
}

// ---------------------------------------------------------------------------
// Kernel 0: x (fp32 [B,C,N]) -> fp16 xf [B,C,N] and transposed xfT [B,N,C].
// 64x64 tiles, float4 loads, LDS transpose.  (unchanged — already ~mem-bound)
// ---------------------------------------------------------------------------
__global__ __launch_bounds__(256) void convert_kernel(const float* __restrict__ x,
                                                      unsigned short* __restrict__ xf,
                                                      unsigned short* __restrict__ xfT) {
  const int b = blockIdx.z;
  const int cy = blockIdx.y * 64;   // C tile origin
  const int nx = blockIdx.x * 64;   // N tile origin
  const int t = threadIdx.x;
  const int r = t >> 4, c4 = (t & 15) * 4;

  __shared__ unsigned T[64][65];    // u32 slots: 2-way-max banking both phases

#pragma unroll
  for (int rr = 0; rr < 64; rr += 16) {
    const int row = rr + r;
    const size_t gi = ((size_t)b * C + cy + row) * N + nx + c4;
    const float4 v = *(const float4*)&x[gi];
    u16x4 h;
    h[0] = f32_to_f16u(v.x); h[1] = f32_to_f16u(v.y);
    h[2] = f32_to_f16u(v.z); h[3] = f32_to_f16u(v.w);
    *(u16x4*)&xf[gi] = h;
    T[row][c4 + 0] = h[0]; T[row][c4 + 1] = h[1];
    T[row][c4 + 2] = h[2]; T[row][c4 + 3] = h[3];
  }
  __syncthreads();
#pragma unroll
  for (int rr = 0; rr < 64; rr += 16) {
    const int nrow = rr + r;
    u16x4 o;
    o[0] = (unsigned short)T[c4 + 0][nrow]; o[1] = (unsigned short)T[c4 + 1][nrow];
    o[2] = (unsigned short)T[c4 + 2][nrow]; o[3] = (unsigned short)T[c4 + 3][nrow];
    *(u16x4*)&xfT[((size_t)b * N + nx + nrow) * C + cy + c4] = o;
  }
}

// ---------------------------------------------------------------------------
// Kernel 1 (FULLY FUSED, 8-sub-phase schedule): G = F*F^T -> softmax -> A(LDS)
// -> E=A*F -> out = beta*E + x.
// Each K32 body = 4 sub-phases; sub-phase = {1-5 ds_read + 1 staging piece}
// -> s_barrier -> lgkmcnt(0) -> 4 MFMA (one acc quadrant, setprio-wrapped)
// -> s_barrier.  vmcnt counted ONCE per body (sp3): 11/8/4/0 — staged data is
// always read >=1 barrier after the vmcnt that covers it.  glds 4-buffer ring
// (phase 1) / wave-local reg-staging ping-pong (phase 2).  8 waves x 64x64
// tile, LDS 128 KB, 512 thr, 2 waves/SIMD.
// ---------------------------------------------------------------------------
__global__ __launch_bounds__(512, 2) void gram_soft_av(const unsigned short* __restrict__ xf,
                                                       const unsigned short* __restrict__ xfT,
                                                       const float* __restrict__ beta,
                                                       float* __restrict__ out) {
  const int l = blockIdx.x;
  const int xcd = l & 7, seq = l >> 3;     // 32 blocks per XCD
  const int b = xcd + 8 * (seq >> 3);      // 4 batch-groups per XCD (L2 reuse)
  const int i0 = (seq & 7) * 64;           // row-tile origin

  const unsigned short* __restrict__ Fh = xf  + (size_t)b * C * N;
  const unsigned short* __restrict__ FT = xfT + (size_t)b * N * C;
  float* __restrict__ ob = out + (size_t)b * C * N;

  // 4 x 32 KB staging buffers; Pb[2..3] double as the 64 KB fp16 Atile.
  __shared__ __align__(16) unsigned short Pb[4][512 * 32];   // 128 KB
  unsigned short* Atile = &Pb[2][0];                         // 64 x 512 fp16

  const int t = threadIdx.x, wave = t >> 6, lane = t & 63;   // 8 waves
  const int lrow = lane & 15, quad = lane >> 4;
  const int srow = lane >> 2;                              // row in 16-row chunk
  const int sel  = ((lane & 3) ^ ((lane >> 3) & 3)) * 8;   // swizzled src granule

  f32x4 acc[4][4] = {};   // wave tile 64x64: [ti 4 row-frags][tj 4 col-frags]

#define BAR()   __builtin_amdgcn_s_barrier()
#define LGKM0() asm volatile("s_waitcnt lgkmcnt(0)" ::: "memory"); \
                __builtin_amdgcn_sched_barrier(0)

  // ========================= Phase 1: Gram G = F F^T =========================
#define RD_A1(DST, ti)                                                    \
  { const int r = i0 + (ti) * 16 + lrow;                                  \
    DST = *(const f16x8*)&Pc[r * 32 + (quad ^ ((r >> 1) & 3)) * 8]; }
#define RD_B1(DST, tj)                                                    \
  { const int r = wave * 64 + (tj) * 16 + lrow;                           \
    DST = *(const f16x8*)&Pc[r * 32 + (quad ^ ((r >> 1) & 3)) * 8]; }
#define G1(cc)                                                            \
  if (j < 28) {                                                           \
    const int row = (wave * 4 + (cc)) * 16 + srow;                        \
    glds16(Fh + (size_t)row * N + k4 + sel, &Pb[nb4][(wave * 4 + (cc)) * 512]); \
  }
#define MF(p, AH, BH0, BH1, BH2, BH3, ACC)                                \
  {                                                                       \
    __builtin_amdgcn_s_setprio(1);                                        \
    ACC[p][0] = __builtin_amdgcn_mfma_f32_16x16x32_f16(AH, BH0, ACC[p][0], 0, 0, 0); \
    ACC[p][1] = __builtin_amdgcn_mfma_f32_16x16x32_f16(AH, BH1, ACC[p][1], 0, 0, 0); \
    ACC[p][2] = __builtin_amdgcn_mfma_f32_16x16x32_f16(AH, BH2, ACC[p][2], 0, 0, 0); \
    ACC[p][3] = __builtin_amdgcn_mfma_f32_16x16x32_f16(AH, BH3, ACC[p][3], 0, 0, 0); \
    __builtin_amdgcn_s_setprio(0);                                        \
  }

  // prologue: fill the 4-ring; buffer 0 landed before first read
  {
#pragma unroll
    for (int s = 0; s < 4; ++s)
#pragma unroll
      for (int cc = 0; cc < 4; ++cc) {
        const int row = (wave * 4 + cc) * 16 + srow;
        glds16(Fh + (size_t)row * N + s * 32 + sel, &Pb[s][(wave * 4 + cc) * 512]);
      }
    asm volatile("s_waitcnt vmcnt(12)" ::: "memory");   // stage 0 landed
    BAR();
  }

  for (int j = 0; j < 32; ++j) {
    const unsigned short* __restrict__ Pc = Pb[j & 3];
    const int k4 = (j + 4) * 32;
    const int nb4 = (j + 4) & 3;
    f16x8 bh0, bh1, bh2, bh3, ah;

    // ---- sp0: all B-frags + A0; stage piece 0
    RD_B1(bh0, 0); RD_B1(bh1, 1); RD_B1(bh2, 2); RD_B1(bh3, 3);
    RD_A1(ah, 0);
    G1(0);
    BAR(); LGKM0();
    MF(0, ah, bh0, bh1, bh2, bh3, acc);
    BAR();
    // ---- sp1
    RD_A1(ah, 1);
    G1(1);
    BAR(); LGKM0();
    MF(1, ah, bh0, bh1, bh2, bh3, acc);
    BAR();
    // ---- sp2
    RD_A1(ah, 2);
    G1(2);
    BAR(); LGKM0();
    MF(2, ah, bh0, bh1, bh2, bh3, acc);
    BAR();
    // ---- sp3: counted vmcnt (stage j+1 landed for next body), stage piece 3
    RD_A1(ah, 3);
    if (j < 28)       asm volatile("s_waitcnt vmcnt(11)" ::: "memory");
    else if (j == 28) asm volatile("s_waitcnt vmcnt(8)"  ::: "memory");
    else if (j == 29) asm volatile("s_waitcnt vmcnt(4)"  ::: "memory");
    else              asm volatile("s_waitcnt vmcnt(0)"  ::: "memory");
    G1(3);
    BAR(); LGKM0();
    MF(3, ah, bh0, bh1, bh2, bh3, acc);
    BAR();
  }
#undef G1
#undef RD_A1
#undef RD_B1

  // ==================== fused softmax (rows complete in block) ===============
  // Each wave holds all 64 rows x its 64-col strip; row = ti*16 + quad*4 + rr.
  __syncthreads();                    // all MFMA LDS reads done; reuse LDS
  float* red = (float*)&Pb[0][0];     // 8 waves x 64 row-slots
  float* fin = red + 512;             // 64 finals

  float m[16];
#pragma unroll
  for (int ti = 0; ti < 4; ++ti)
#pragma unroll
    for (int rr = 0; rr < 4; ++rr)
      m[ti * 4 + rr] = fminf(fminf(acc[ti][0][rr], acc[ti][1][rr]),
                             fminf(acc[ti][2][rr], acc[ti][3][rr]));
#pragma unroll
  for (int o = 1; o < 16; o <<= 1)
#pragma unroll
    for (int s = 0; s < 16; ++s) m[s] = fminf(m[s], __shfl_xor(m[s], o, 64));
  if (lrow == 0)
#pragma unroll
    for (int ti = 0; ti < 4; ++ti)
#pragma unroll
      for (int rr = 0; rr < 4; ++rr)
        red[wave * 64 + ti * 16 + quad * 4 + rr] = m[ti * 4 + rr];
  __syncthreads();
  if (t < 64) {
    float v = red[t];
#pragma unroll
    for (int j = 1; j < 8; ++j) v = fminf(v, red[j * 64 + t]);
    fin[t] = v;
  }
  __syncthreads();

  // exponentiate in place, per-lane partial row sums
  float sm[16];
#pragma unroll
  for (int ti = 0; ti < 4; ++ti)
#pragma unroll
    for (int rr = 0; rr < 4; ++rr) {
      const float mn = fin[ti * 16 + quad * 4 + rr];
      float s = 0.f;
#pragma unroll
      for (int tj = 0; tj < 4; ++tj) {
        const float e = __expf(mn - acc[ti][tj][rr]);
        acc[ti][tj][rr] = e;
        s += e;
      }
      sm[ti * 4 + rr] = s;
    }
#pragma unroll
  for (int o = 1; o < 16; o <<= 1)
#pragma unroll
    for (int s = 0; s < 16; ++s) sm[s] += __shfl_xor(sm[s], o, 64);
  if (lrow == 0)
#pragma unroll
    for (int ti = 0; ti < 4; ++ti)
#pragma unroll
      for (int rr = 0; rr < 4; ++rr)
        red[wave * 64 + ti * 16 + quad * 4 + rr] = sm[ti * 4 + rr];
  __syncthreads();
  if (t < 64) {
    float v = 0.f;
#pragma unroll
    for (int j = 0; j < 8; ++j) v += red[j * 64 + t];
    fin[t] = 1.0f / v;
  }
  __syncthreads();

  // scale + write fp16 A into LDS Atile (= Pb[2..3]), XOR-swizzled:
  // element (r,c) at r*512 + ((c>>3 ^ (r&7))*8 | (c&7)).
#pragma unroll
  for (int ti = 0; ti < 4; ++ti)
#pragma unroll
    for (int rr = 0; rr < 4; ++rr) {
      const float inv = fin[ti * 16 + quad * 4 + rr];
      const int rl = ti * 16 + quad * 4 + rr;             // local row 0..63
#pragma unroll
      for (int tj = 0; tj < 4; ++tj) {
        const int gcol = wave * 64 + tj * 16 + lrow;
        Atile[rl * 512 + ((((gcol >> 3) ^ (rl & 7)) << 3) | (gcol & 7))] =
            f32_to_f16u(acc[ti][tj][rr] * inv);
      }
    }
  __syncthreads();                    // Atile visible to all waves; red/fin dead

  // ======================= Phase 2: E = A*F, out = beta*E + x ================
  // 2 column-half passes of 512.  B-panels are wave-local (each wave stages
  // and reads only its own 64-row strip); same 4-sub-phase schedule.
  const float bv = beta[0];

  for (int jp = 0; jp < 2; ++jp) {
    f32x4 eacc[4][4] = {};
    u16x8 rsA[4];
#define LOADR_E(k0, c0, c1)                                                    \
    {                                                                          \
      rsA[c0] = *(const u16x8*)&FT[(size_t)(jp * 512 + (wave * 4 + (c0)) * 16 + srow) * C + (k0) + sel]; \
      rsA[c1] = *(const u16x8*)&FT[(size_t)(jp * 512 + (wave * 4 + (c1)) * 16 + srow) * C + (k0) + sel]; \
    }
#define WRITER_E(nb)                                                           \
    {                                                                          \
      _Pragma("unroll")                                                        \
      for (int cc = 0; cc < 4; ++cc)                                           \
        *(u16x8*)&Pb[nb][(wave * 4 + cc) * 512 + lane * 8] = rsA[cc];          \
    }
#define RD_A2(DST, ti)                                                         \
    { const int ra = (ti) * 16 + lrow;                                         \
      DST = *(const f16x8*)&Atile[ra * 512 + ((((kk >> 3) + quad) ^ (ra & 7)) << 3)]; }
#define RD_B2(DST, tj)                                                         \
    { const int rb = wave * 64 + (tj) * 16 + lrow;                             \
      DST = *(const f16x8*)&Pc2[rb * 32 + ((quad ^ ((rb >> 1) & 3)) << 3)]; }

    LOADR_E(0, 0, 1); LOADR_E(0, 2, 3);
    WRITER_E(0);          // compiler inserts vmcnt wait for rsA dep
    LOADR_E(32, 0, 1); LOADR_E(32, 2, 3);   // prefetch panel 1 into regs
    LGKM0();
    BAR();

    for (int u = 0; u < 16; ++u) {
      const unsigned short* __restrict__ Pc2 = Pb[u & 1];
      const int kk = u * 32;
      f16x8 bh0, bh1, bh2, bh3, ah;

      // ---- sp0: all B-frags + A0
      RD_B2(bh0, 0); RD_B2(bh1, 1); RD_B2(bh2, 2); RD_B2(bh3, 3);
      RD_A2(ah, 0);
      BAR(); LGKM0();
      MF(0, ah, bh0, bh1, bh2, bh3, eacc);
      BAR();
      // ---- sp1: write next panel from regs
      RD_A2(ah, 1);
      if (u + 1 < 16) WRITER_E((u + 1) & 1);
      BAR(); LGKM0();
      MF(1, ah, bh0, bh1, bh2, bh3, eacc);
      BAR();
      // ---- sp2: load next-next panel, half 0
      RD_A2(ah, 2);
      if (u + 2 < 16) LOADR_E((u + 2) * 32, 0, 1);
      BAR(); LGKM0();
      MF(2, ah, bh0, bh1, bh2, bh3, eacc);
      BAR();
      // ---- sp3: load next-next panel, half 1
      RD_A2(ah, 3);
      if (u + 2 < 16) LOADR_E((u + 2) * 32, 2, 3);
      BAR(); LGKM0();
      MF(3, ah, bh0, bh1, bh2, bh3, eacc);
      BAR();
    }
#undef RD_B2
#undef RD_A2
#undef WRITER_E
#undef LOADR_E

    // Epilogue: per-wave LDS transpose (own 4 KB region -> no block barriers),
    // residual from fp16 xf (|err| <= |x|*4.9e-4), nontemporal stores.
    float* fs = (float*)&Pb[0][0] + wave * 1024;   // 4 KB per wave
#pragma unroll
    for (int ti = 0; ti < 4; ++ti) {
#pragma unroll
      for (int tj = 0; tj < 4; ++tj)
#pragma unroll
        for (int r = 0; r < 4; ++r)
          fs[(quad * 4 + r) * 64 + tj * 16 + lrow] = eacc[ti][tj][r];
      asm volatile("s_waitcnt lgkmcnt(0)" ::: "memory");   // per-wave RAW fence
#pragma unroll
      for (int p = 0; p < 4; ++p) {
        const int f = p * 64 + lane;
        const int rr2 = f >> 4, cc4 = (f & 15) * 4;
        const f32x4 e = *(const f32x4*)&fs[rr2 * 64 + cc4];
        const int gr = i0 + ti * 16 + rr2;
        const int gc = jp * 512 + wave * 64 + cc4;
        const size_t o = (size_t)gr * N + gc;
        const u16x4 xv = *(const u16x4*)&Fh[o];
        f32x4 ov;
        ov[0] = fmaf(bv, e[0], f16u_to_f32(xv[0]));
        ov[1] = fmaf(bv, e[1], f16u_to_f32(xv[1]));
        ov[2] = fmaf(bv, e[2], f16u_to_f32(xv[2]));
        ov[3] = fmaf(bv, e[3], f16u_to_f32(xv[3]));
        __builtin_nontemporal_store(ov, (f32x4*)&ob[o]);
      }
      asm volatile("s_waitcnt lgkmcnt(0)" ::: "memory");   // WAR vs next ds ops
    }
  }
#undef MF
#undef BAR
#undef LGKM0
}

// ---------------------------------------------------------------------------
extern "C" void kernel_launch(void* const* d_in, const int* in_sizes, int n_in,
                              void* d_out, int out_size, void* d_ws, size_t ws_size,
                              hipStream_t stream) {
  const float* x    = (const float*)d_in[0];
  const float* beta = (const float*)d_in[1];
  float* out = (float*)d_out;

  char* ws = (char*)d_ws;
  unsigned short* xf  = (unsigned short*)ws; ws += (size_t)B * C * N * 2;  // 32 MB
  unsigned short* xfT = (unsigned short*)ws;                               // 32 MB

  convert_kernel<<<dim3(N / 64, C / 64, B), dim3(256), 0, stream>>>(x, xf, xfT);
  gram_soft_av  <<<dim3(256),               dim3(512), 0, stream>>>(xf, xfT, beta, out);
}